// Round 28
// baseline (202.239 us; speedup 1.0000x reference)
//
#include <hip/hip_runtime.h>

typedef __attribute__((ext_vector_type(8))) short short8;
typedef __attribute__((ext_vector_type(4))) float f32x4;
typedef __attribute__((ext_vector_type(2))) float f32x2;
typedef unsigned short u16;
typedef unsigned int u32;

#define MFMA16(a, b, c) __builtin_amdgcn_mfma_f32_16x16x32_bf16((a), (b), (c), 0, 0, 0)
#define SCALE 0.044194173824159216f /* 1/sqrt(512) */

// LDS swizzle for the u16 [32][1024] tile: XOR row bits into the 8-u16 (16B)
// granule index so stride-2KB row accesses spread across banks (m136/m201).
#define SW(r, c) ((c) ^ (((r) & 7) << 3))

__device__ __forceinline__ u16 f2bf(float f) {
    u32 u = __float_as_uint(f);
    u = (u + 0x7fffu + ((u >> 16) & 1u)) >> 16; // RNE
    return (u16)u;
}

__global__ __launch_bounds__(256) void cvt_kernel(const float* __restrict__ src,
                                                  u16* __restrict__ dst, int n4) {
    int i = blockIdx.x * 256 + threadIdx.x;
    if (i >= n4) return;
    float4 v = ((const float4*)src)[i];
    unsigned long long p = (unsigned long long)f2bf(v.x)
                         | ((unsigned long long)f2bf(v.y) << 16)
                         | ((unsigned long long)f2bf(v.z) << 32)
                         | ((unsigned long long)f2bf(v.w) << 48);
    ((unsigned long long*)dst)[i] = p;
}

// rel[r,c] = sum_k pos_emb[r,k] * Wp[c,k] + bp[c], r<2047, c<64 -> bf16
__global__ __launch_bounds__(256) void rel_kernel(const float* __restrict__ pos_emb,
                                                  const float* __restrict__ Wp,
                                                  const float* __restrict__ bp,
                                                  u16* __restrict__ rel) {
    int idx = blockIdx.x * 256 + threadIdx.x;
    if (idx >= 2047 * 64) return;
    int r = idx >> 6, c = idx & 63;
    const float* pe = pos_emb + r * 64;
    const float* w  = Wp + c * 64;
    float acc = bp[c];
#pragma unroll
    for (int k = 0; k < 64; k++) acc += pe[k] * w[k];
    rel[r * 64 + c] = f2bf(acc);
}

// C[M,N] = A[M,K] @ B[N,K]^T, bf16 inputs, 64x64 block tile, 4 waves 2x2.
// MODE 0: q/k proj -> bf16 [B,H,S,dh], bias[n]  (grid (64,8): A-panel
//   sharers are 64 apart -> already same-XCD under round-robin; fine)
// MODE 2: final -> fp32 row-major, bias[n]
template <int MODE>
__global__ __launch_bounds__(256) void gemm_kernel(const u16* __restrict__ A,
                                                   const u16* __restrict__ B,
                                                   const float* __restrict__ bias,
                                                   void* __restrict__ Cout,
                                                   int M, int N, int K) {
    int tid = threadIdx.x;
    int w = tid >> 6, lane = tid & 63;
    int wi = w >> 1, wj = w & 1;
    int qd = lane >> 4, ln = lane & 15;
    int m_base = blockIdx.x * 64 + wi * 32;
    int n_base = blockIdx.y * 64 + wj * 32;
    f32x4 acc[2][2] = {};
    const u16* a0p = A + (long)(m_base + ln) * K + qd * 8;
    const u16* a1p = a0p + 16 * K;
    const u16* b0p = B + (long)(n_base + ln) * K + qd * 8;
    const u16* b1p = b0p + 16 * K;
    for (int kc = 0; kc < K; kc += 32) {
        short8 a0 = *(const short8*)(a0p + kc);
        short8 a1 = *(const short8*)(a1p + kc);
        short8 b0 = *(const short8*)(b0p + kc);
        short8 b1 = *(const short8*)(b1p + kc);
        acc[0][0] = MFMA16(a0, b0, acc[0][0]);
        acc[0][1] = MFMA16(a0, b1, acc[0][1]);
        acc[1][0] = MFMA16(a1, b0, acc[1][0]);
        acc[1][1] = MFMA16(a1, b1, acc[1][1]);
    }
#pragma unroll
    for (int i = 0; i < 2; i++)
#pragma unroll
        for (int j = 0; j < 2; j++)
#pragma unroll
            for (int r = 0; r < 4; r++) {
                int m = m_base + i * 16 + qd * 4 + r;
                int n = n_base + j * 16 + ln;
                float v = acc[i][j][r];
                if (MODE == 0) {
                    v += bias[n];
                    int b = m >> 10, s = m & 1023, h = n >> 6, d = n & 63;
                    ((u16*)Cout)[(((long)(b * 8 + h) << 10) + s) * 64 + d] = f2bf(v);
                } else {
                    v += bias[n];
                    ((float*)Cout)[(long)m * N + n] = v;
                }
            }
}

// V-projection: vT[B,H,dh,S] = Wv @ value^T, bias[m]. T1 XCD swizzle (R22,
// neutral-but-sound): 1D grid(512), same-y panel sharers -> same XCD.
__global__ __launch_bounds__(256) void gemm_v_kernel(const u16* __restrict__ A,
                                                     const u16* __restrict__ B,
                                                     const float* __restrict__ bias,
                                                     u16* __restrict__ Cout) {
    constexpr int K = 512;
    int i = blockIdx.x;
    int c = i & 7;
    int t = i >> 3;
    int bx = t & 7;              // m tile (dh block), M = 512
    int by = c + 8 * (t >> 3);   // n tile (t block), N = 4096
    int tid = threadIdx.x;
    int w = tid >> 6, lane = tid & 63;
    int wi = w >> 1, wj = w & 1;
    int qd = lane >> 4, ln = lane & 15;
    int m_base = bx * 64 + wi * 32;
    int n_base = by * 64 + wj * 32;
    f32x4 acc[2][2] = {};
    const u16* a0p = A + (long)(m_base + ln) * K + qd * 8;
    const u16* a1p = a0p + 16 * K;
    const u16* b0p = B + (long)(n_base + ln) * K + qd * 8;
    const u16* b1p = b0p + 16 * K;
    for (int kc = 0; kc < K; kc += 32) {
        short8 a0 = *(const short8*)(a0p + kc);
        short8 a1 = *(const short8*)(a1p + kc);
        short8 b0 = *(const short8*)(b0p + kc);
        short8 b1 = *(const short8*)(b1p + kc);
        acc[0][0] = MFMA16(a0, b0, acc[0][0]);
        acc[0][1] = MFMA16(a0, b1, acc[0][1]);
        acc[1][0] = MFMA16(a1, b0, acc[1][0]);
        acc[1][1] = MFMA16(a1, b1, acc[1][1]);
    }
#pragma unroll
    for (int ii = 0; ii < 2; ii++)
#pragma unroll
        for (int j = 0; j < 2; j++)
#pragma unroll
            for (int r = 0; r < 4; r++) {
                int m = m_base + ii * 16 + qd * 4 + r;
                int n = n_base + j * 16 + ln;
                float v = acc[ii][j][r] + bias[m];
                int b = n >> 10, tt = n & 1023, h = m >> 6, d = m & 63;
                Cout[(((long)(b * 8 + h) * 64 + d) << 10) + tt] = f2bf(v);
            }
}

// One block per (b, h, 32-row s-tile). 256 threads = 4 waves. 2 barriers total.
// Body identical to the locked R5 kernel; T1 XCD-aware block decode (R21,
// measured 214.1 -> 201.8 us): 1D grid(1024), i = (g&7) + 8*(st + 32*(g>>3))
// so all 32 s-tiles of one (b,h) group g land on XCD g%8 -> shared K/V^T
// panels fetched once per XCD instead of 8x. Bijective (1024 % 8 == 0).
// FINAL (converged, 200.3-202.4 us across 5 runs): one validated win (T1),
// 11 other interventions regressed or aborted; this is the optimum.
__global__ __launch_bounds__(256) void score_kernel(const u16* __restrict__ qws,
                                                    const u16* __restrict__ kws,
                                                    const u16* __restrict__ vtws,
                                                    const u16* __restrict__ relws,
                                                    float* __restrict__ out_attn,
                                                    float* __restrict__ out_cont,
                                                    float* __restrict__ out_pos,
                                                    u16* __restrict__ ctx,
                                                    float* __restrict__ sinvws) {
    __shared__ __align__(16) u16 sc[32][1024]; // 64 KB
    // T1 decode: invert i = (g&7) + 8*(st + 32*(g>>3))
    int i = blockIdx.x;
    int xcd = i & 7;
    int j = i >> 3;
    int st = j & 31;
    int g = ((j >> 5) << 3) | xcd; // bh group 0..31
    int h = g & 7, b = g >> 3;
    int s0 = st * 32;
    int tid = threadIdx.x;
    int w = tid >> 6, lane = tid & 63, qd = lane >> 4, ln = lane & 15;
    int bh = b * 8 + h;
    int c0 = w * 256;

    const u16* qbase  = qws + ((long)bh << 10) * 64;   // [1024][64]
    const u16* kbase  = kws + ((long)bh << 10) * 64;   // [1024][64]
    const u16* vtbase = vtws + ((long)bh << 6) * 1024; // [64][1024]
    float* attn_base = out_attn + ((long)bh << 20) + (long)s0 * 1024;
    float* cont_base = out_cont + ((long)bh << 20) + (long)s0 * 1024;
    float* pos_base  = out_pos  + ((long)bh << 20) + (long)s0 * 1024;

    // q fragments: 2 row-tiles x 2 K-chunks
    short8 qa00 = *(const short8*)(qbase + (s0 + ln) * 64 + qd * 8);
    short8 qa01 = *(const short8*)(qbase + (s0 + ln) * 64 + 32 + qd * 8);
    short8 qa10 = *(const short8*)(qbase + (s0 + 16 + ln) * 64 + qd * 8);
    short8 qa11 = *(const short8*)(qbase + (s0 + 16 + ln) * 64 + 32 + qd * 8);

    // ---- Phase A1: content ----
    for (int tt = 0; tt < 16; tt++) {
        int t0 = c0 + tt * 16;
        const u16* kp = kbase + (t0 + ln) * 64 + qd * 8;
        short8 kb0 = *(const short8*)(kp);
        short8 kb1 = *(const short8*)(kp + 32);
        f32x4 a0 = {}, a1 = {};
        a0 = MFMA16(qa00, kb0, a0);
        a0 = MFMA16(qa01, kb1, a0);
        a1 = MFMA16(qa10, kb0, a1);
        a1 = MFMA16(qa11, kb1, a1);
        int t = t0 + ln;
#pragma unroll
        for (int r = 0; r < 4; r++) {
            int sl = qd * 4 + r;
            cont_base[sl * 1024 + t] = a0[r];
            cont_base[(sl + 16) * 1024 + t] = a1[r];
            sc[sl][SW(sl, t)] = f2bf(a0[r] * SCALE);
            sc[sl + 16][SW(sl + 16, t)] = f2bf(a1[r] * SCALE);
        }
    }

    // ---- Phase A2: pos band (wave-private, no barrier needed) ----
    int rbase = 1008 - s0;
    for (int rt = 16 * w - 1; rt <= 16 * w + 16; rt++) {
        int r0 = rbase + rt * 16; // min 0 (s0=992,w=0,rt=-1); max+ln = 2047
        const u16* rp = relws + (r0 + ln) * 64 + qd * 8;
        short8 rb0 = *(const short8*)(rp);
        short8 rb1 = *(const short8*)(rp + 32);
        f32x4 a0 = {}, a1 = {};
        a0 = MFMA16(qa00, rb0, a0);
        a0 = MFMA16(qa01, rb1, a0);
        a1 = MFMA16(qa10, rb0, a1);
        a1 = MFMA16(qa11, rb1, a1);
#pragma unroll
        for (int r = 0; r < 4; r++) {
            int sl = qd * 4 + r;
            int t = rt * 16 + ln + sl - 15; // row-tile 0
            if (t >= c0 && t < c0 + 256) {
                pos_base[sl * 1024 + t] = a0[r];
                u16 cur = sc[sl][SW(sl, t)];
                float fv = __uint_as_float((u32)cur << 16) + a0[r] * SCALE;
                sc[sl][SW(sl, t)] = f2bf(fv);
            }
            int t1 = t + 16;                // row-tile 1
            if (t1 >= c0 && t1 < c0 + 256) {
                pos_base[(sl + 16) * 1024 + t1] = a1[r];
                u16 cur = sc[sl + 16][SW(sl + 16, t1)];
                float fv = __uint_as_float((u32)cur << 16) + a1[r] * SCALE;
                sc[sl + 16][SW(sl + 16, t1)] = f2bf(fv);
            }
        }
    }
    __syncthreads();

    // ---- Phase B: softmax, 8 threads/row over 32 rows ----
    {
        int row = tid >> 3, gg = tid & 7;
        float sum = 0.f;
#pragma unroll
        for (int ii = 0; ii < 64; ii++) {
            int c = 2 * gg + 16 * ii;
            u32 pk = *(const u32*)&sc[row][SW(row, c)];
            float e0 = __expf(__uint_as_float(pk << 16));
            float e1 = __expf(__uint_as_float(pk & 0xffff0000u));
            sum += e0 + e1;
            u32 pe;
            asm("v_cvt_pk_bf16_f32 %0, %1, %2" : "=v"(pe) : "v"(e0), "v"(e1));
            *(u32*)&sc[row][SW(row, c)] = pe; // in place: this u32 is ours
        }
        sum += __shfl_xor(sum, 1, 8);
        sum += __shfl_xor(sum, 2, 8);
        sum += __shfl_xor(sum, 4, 8);
        float inv = 1.0f / sum;
        if (gg == 0) sinvws[((long)bh << 10) + s0 + row] = inv;
#pragma unroll
        for (int ii = 0; ii < 64; ii++) {
            int c = 2 * gg + 16 * ii;
            u32 pk = *(const u32*)&sc[row][SW(row, c)];
            f32x2 av = {__uint_as_float(pk << 16) * inv,
                        __uint_as_float(pk & 0xffff0000u) * inv};
            *(f32x2*)&attn_base[row * 1024 + c] = av;
        }
    }
    __syncthreads();

    // ---- Phase C: PV. Wave w -> d-subtile [w*16, w*16+16), both row-tiles.
    {
        float inv0[4], inv1[4]; // written pre-barrier by this block
#pragma unroll
        for (int r = 0; r < 4; r++) {
            inv0[r] = sinvws[((long)bh << 10) + s0 + qd * 4 + r];
            inv1[r] = sinvws[((long)bh << 10) + s0 + 16 + qd * 4 + r];
        }
        const u16* vrow = vtbase + (w * 16 + ln) * 1024 + qd * 8;
        f32x4 oa00 = {}, oa01 = {}, oa10 = {}, oa11 = {};
#pragma unroll
        for (int kt = 0; kt < 32; kt += 2) {
            int ca = kt * 32 + qd * 8;
            int cb = ca + 32;
            short8 a0  = *(const short8*)&sc[ln][SW(ln, ca)];
            short8 a1  = *(const short8*)&sc[ln + 16][SW(ln + 16, ca)];
            short8 b0  = *(const short8*)(vrow + kt * 32);
            short8 a0b = *(const short8*)&sc[ln][SW(ln, cb)];
            short8 a1b = *(const short8*)&sc[ln + 16][SW(ln + 16, cb)];
            short8 b1  = *(const short8*)(vrow + kt * 32 + 32);
            oa00 = MFMA16(a0, b0, oa00);
            oa10 = MFMA16(a1, b0, oa10);
            oa01 = MFMA16(a0b, b1, oa01);
            oa11 = MFMA16(a1b, b1, oa11);
        }
        int d = w * 16 + ln;
#pragma unroll
        for (int r = 0; r < 4; r++) {
            int sl = qd * 4 + r;
            ctx[((long)(b * 1024 + s0 + sl)) * 512 + h * 64 + d] =
                f2bf((oa00[r] + oa01[r]) * inv0[r]);
            ctx[((long)(b * 1024 + s0 + 16 + sl)) * 512 + h * 64 + d] =
                f2bf((oa10[r] + oa11[r]) * inv1[r]);
        }
    }
}

extern "C" void kernel_launch(void* const* d_in, const int* in_sizes, int n_in,
                              void* d_out, int out_size, void* d_ws, size_t ws_size,
                              hipStream_t stream) {
    (void)in_sizes; (void)n_in; (void)out_size; (void)ws_size;
    const float* query   = (const float*)d_in[0];
    const float* key     = (const float*)d_in[1];
    const float* value   = (const float*)d_in[2];
    const float* pos_emb = (const float*)d_in[3];
    const float* Wq = (const float*)d_in[4];
    const float* bq = (const float*)d_in[5];
    const float* Wk = (const float*)d_in[6];
    const float* bk = (const float*)d_in[7];
    const float* Wv = (const float*)d_in[8];
    const float* bv = (const float*)d_in[9];
    const float* Wo = (const float*)d_in[10];
    const float* bo = (const float*)d_in[11];
    const float* Wp = (const float*)d_in[12];
    const float* bp = (const float*)d_in[13];

    // workspace layout (bf16 u16 elements)
    u16* qin  = (u16*)d_ws;            // 4096*512
    u16* kin  = qin + 4096 * 512;
    u16* vin  = kin + 4096 * 512;
    u16* wqb  = vin + 4096 * 512;      // 512*512 each
    u16* wkb  = wqb + 512 * 512;
    u16* wvb  = wkb + 512 * 512;
    u16* wob  = wvb + 512 * 512;
    u16* relb = wob + 512 * 512;       // 2048*64 (row 2047 read-garbage, discarded)
    u16* qws  = relb + 2048 * 64;      // [B,H,S,64]
    u16* kws  = qws + 4 * 8 * 1024 * 64;
    u16* vtws = kws + 4 * 8 * 1024 * 64; // [B,H,64,S]
    u16* ctx  = qin;                   // alias: qin dead after q-projection
    float* sinvws = (float*)kin;       // alias: kin dead after k-projection

    float* out  = (float*)d_out;
    float* attn = out + 2097152;
    float* cont = attn + 33554432;
    float* pos  = cont + 33554432;

    cvt_kernel<<<2048, 256, 0, stream>>>(query, qin, 524288);
    cvt_kernel<<<2048, 256, 0, stream>>>(key, kin, 524288);
    cvt_kernel<<<2048, 256, 0, stream>>>(value, vin, 524288);
    cvt_kernel<<<256, 256, 0, stream>>>(Wq, wqb, 65536);
    cvt_kernel<<<256, 256, 0, stream>>>(Wk, wkb, 65536);
    cvt_kernel<<<256, 256, 0, stream>>>(Wv, wvb, 65536);
    cvt_kernel<<<256, 256, 0, stream>>>(Wo, wob, 65536);
    rel_kernel<<<512, 256, 0, stream>>>(pos_emb, Wp, bp, relb);

    gemm_kernel<0><<<dim3(64, 8), 256, 0, stream>>>(qin, wqb, bq, qws, 4096, 512, 512);
    gemm_kernel<0><<<dim3(64, 8), 256, 0, stream>>>(kin, wkb, bk, kws, 4096, 512, 512);
    gemm_v_kernel<<<512, 256, 0, stream>>>(wvb, vin, bv, vtws);

    score_kernel<<<1024, 256, 0, stream>>>(qws, kws, vtws, relb,
                                           attn, cont, pos, ctx, sinvws);

    gemm_kernel<2><<<dim3(64, 8), 256, 0, stream>>>(ctx, wob, bo, out, 4096, 512, 512);
}

// Round 29
// 196.878 us; speedup vs baseline: 1.0272x; 1.0272x over previous
//
#include <hip/hip_runtime.h>

typedef __attribute__((ext_vector_type(8))) short short8;
typedef __attribute__((ext_vector_type(4))) float f32x4;
typedef __attribute__((ext_vector_type(2))) float f32x2;
typedef unsigned short u16;
typedef unsigned int u32;

#define MFMA16(a, b, c) __builtin_amdgcn_mfma_f32_16x16x32_bf16((a), (b), (c), 0, 0, 0)
#define SCALE 0.044194173824159216f /* 1/sqrt(512) */

// LDS swizzle for the u16 [32][1024] tile: XOR row bits into the 8-u16 (16B)
// granule index so stride-2KB row accesses spread across banks (m136/m201).
#define SW(r, c) ((c) ^ (((r) & 7) << 3))

__device__ __forceinline__ u16 f2bf(float f) {
    u32 u = __float_as_uint(f);
    u = (u + 0x7fffu + ((u >> 16) & 1u)) >> 16; // RNE
    return (u16)u;
}

__global__ __launch_bounds__(256) void cvt_kernel(const float* __restrict__ src,
                                                  u16* __restrict__ dst, int n4) {
    int i = blockIdx.x * 256 + threadIdx.x;
    if (i >= n4) return;
    float4 v = ((const float4*)src)[i];
    unsigned long long p = (unsigned long long)f2bf(v.x)
                         | ((unsigned long long)f2bf(v.y) << 16)
                         | ((unsigned long long)f2bf(v.z) << 32)
                         | ((unsigned long long)f2bf(v.w) << 48);
    ((unsigned long long*)dst)[i] = p;
}

// rel[r,c] = sum_k pos_emb[r,k] * Wp[c,k] + bp[c], r<2047, c<64 -> bf16
__global__ __launch_bounds__(256) void rel_kernel(const float* __restrict__ pos_emb,
                                                  const float* __restrict__ Wp,
                                                  const float* __restrict__ bp,
                                                  u16* __restrict__ rel) {
    int idx = blockIdx.x * 256 + threadIdx.x;
    if (idx >= 2047 * 64) return;
    int r = idx >> 6, c = idx & 63;
    const float* pe = pos_emb + r * 64;
    const float* w  = Wp + c * 64;
    float acc = bp[c];
#pragma unroll
    for (int k = 0; k < 64; k++) acc += pe[k] * w[k];
    rel[r * 64 + c] = f2bf(acc);
}

// C[M,N] = A[M,K] @ B[N,K]^T, bf16 inputs, 64x64 block tile, 4 waves 2x2.
// MODE 0: q/k proj -> bf16 [B,H,S,dh], bias[n]  (grid (64,8): A-panel
//   sharers are 64 apart -> already same-XCD under round-robin; fine)
// MODE 2: final -> fp32 row-major, bias[n]
template <int MODE>
__global__ __launch_bounds__(256) void gemm_kernel(const u16* __restrict__ A,
                                                   const u16* __restrict__ B,
                                                   const float* __restrict__ bias,
                                                   void* __restrict__ Cout,
                                                   int M, int N, int K) {
    int tid = threadIdx.x;
    int w = tid >> 6, lane = tid & 63;
    int wi = w >> 1, wj = w & 1;
    int qd = lane >> 4, ln = lane & 15;
    int m_base = blockIdx.x * 64 + wi * 32;
    int n_base = blockIdx.y * 64 + wj * 32;
    f32x4 acc[2][2] = {};
    const u16* a0p = A + (long)(m_base + ln) * K + qd * 8;
    const u16* a1p = a0p + 16 * K;
    const u16* b0p = B + (long)(n_base + ln) * K + qd * 8;
    const u16* b1p = b0p + 16 * K;
    for (int kc = 0; kc < K; kc += 32) {
        short8 a0 = *(const short8*)(a0p + kc);
        short8 a1 = *(const short8*)(a1p + kc);
        short8 b0 = *(const short8*)(b0p + kc);
        short8 b1 = *(const short8*)(b1p + kc);
        acc[0][0] = MFMA16(a0, b0, acc[0][0]);
        acc[0][1] = MFMA16(a0, b1, acc[0][1]);
        acc[1][0] = MFMA16(a1, b0, acc[1][0]);
        acc[1][1] = MFMA16(a1, b1, acc[1][1]);
    }
#pragma unroll
    for (int i = 0; i < 2; i++)
#pragma unroll
        for (int j = 0; j < 2; j++)
#pragma unroll
            for (int r = 0; r < 4; r++) {
                int m = m_base + i * 16 + qd * 4 + r;
                int n = n_base + j * 16 + ln;
                float v = acc[i][j][r];
                if (MODE == 0) {
                    v += bias[n];
                    int b = m >> 10, s = m & 1023, h = n >> 6, d = n & 63;
                    ((u16*)Cout)[(((long)(b * 8 + h) << 10) + s) * 64 + d] = f2bf(v);
                } else {
                    v += bias[n];
                    ((float*)Cout)[(long)m * N + n] = v;
                }
            }
}

// V-projection: vT[B,H,dh,S] = Wv @ value^T, bias[m]. T1 XCD swizzle (R22,
// neutral-but-sound): 1D grid(512), same-y panel sharers -> same XCD.
__global__ __launch_bounds__(256) void gemm_v_kernel(const u16* __restrict__ A,
                                                     const u16* __restrict__ B,
                                                     const float* __restrict__ bias,
                                                     u16* __restrict__ Cout) {
    constexpr int K = 512;
    int i = blockIdx.x;
    int c = i & 7;
    int t = i >> 3;
    int bx = t & 7;              // m tile (dh block), M = 512
    int by = c + 8 * (t >> 3);   // n tile (t block), N = 4096
    int tid = threadIdx.x;
    int w = tid >> 6, lane = tid & 63;
    int wi = w >> 1, wj = w & 1;
    int qd = lane >> 4, ln = lane & 15;
    int m_base = bx * 64 + wi * 32;
    int n_base = by * 64 + wj * 32;
    f32x4 acc[2][2] = {};
    const u16* a0p = A + (long)(m_base + ln) * K + qd * 8;
    const u16* a1p = a0p + 16 * K;
    const u16* b0p = B + (long)(n_base + ln) * K + qd * 8;
    const u16* b1p = b0p + 16 * K;
    for (int kc = 0; kc < K; kc += 32) {
        short8 a0 = *(const short8*)(a0p + kc);
        short8 a1 = *(const short8*)(a1p + kc);
        short8 b0 = *(const short8*)(b0p + kc);
        short8 b1 = *(const short8*)(b1p + kc);
        acc[0][0] = MFMA16(a0, b0, acc[0][0]);
        acc[0][1] = MFMA16(a0, b1, acc[0][1]);
        acc[1][0] = MFMA16(a1, b0, acc[1][0]);
        acc[1][1] = MFMA16(a1, b1, acc[1][1]);
    }
#pragma unroll
    for (int ii = 0; ii < 2; ii++)
#pragma unroll
        for (int j = 0; j < 2; j++)
#pragma unroll
            for (int r = 0; r < 4; r++) {
                int m = m_base + ii * 16 + qd * 4 + r;
                int n = n_base + j * 16 + ln;
                float v = acc[ii][j][r] + bias[m];
                int b = n >> 10, tt = n & 1023, h = m >> 6, d = m & 63;
                Cout[(((long)(b * 8 + h) * 64 + d) << 10) + tt] = f2bf(v);
            }
}

// One block per (b, h, 32-row s-tile). 256 threads = 4 waves. 2 barriers total.
// Body identical to the locked R5 kernel; T1 XCD-aware block decode (R21,
// measured 214.1 -> 201.8 us): 1D grid(1024), i = (g&7) + 8*(st + 32*(g>>3))
// so all 32 s-tiles of one (b,h) group g land on XCD g%8 -> shared K/V^T
// panels fetched once per XCD instead of 8x. Bijective (1024 % 8 == 0).
// FINAL (converged, 200.3-202.4 us across 6 runs): one validated win (T1),
// 11 other interventions regressed or aborted; this is the optimum.
__global__ __launch_bounds__(256) void score_kernel(const u16* __restrict__ qws,
                                                    const u16* __restrict__ kws,
                                                    const u16* __restrict__ vtws,
                                                    const u16* __restrict__ relws,
                                                    float* __restrict__ out_attn,
                                                    float* __restrict__ out_cont,
                                                    float* __restrict__ out_pos,
                                                    u16* __restrict__ ctx,
                                                    float* __restrict__ sinvws) {
    __shared__ __align__(16) u16 sc[32][1024]; // 64 KB
    // T1 decode: invert i = (g&7) + 8*(st + 32*(g>>3))
    int i = blockIdx.x;
    int xcd = i & 7;
    int j = i >> 3;
    int st = j & 31;
    int g = ((j >> 5) << 3) | xcd; // bh group 0..31
    int h = g & 7, b = g >> 3;
    int s0 = st * 32;
    int tid = threadIdx.x;
    int w = tid >> 6, lane = tid & 63, qd = lane >> 4, ln = lane & 15;
    int bh = b * 8 + h;
    int c0 = w * 256;

    const u16* qbase  = qws + ((long)bh << 10) * 64;   // [1024][64]
    const u16* kbase  = kws + ((long)bh << 10) * 64;   // [1024][64]
    const u16* vtbase = vtws + ((long)bh << 6) * 1024; // [64][1024]
    float* attn_base = out_attn + ((long)bh << 20) + (long)s0 * 1024;
    float* cont_base = out_cont + ((long)bh << 20) + (long)s0 * 1024;
    float* pos_base  = out_pos  + ((long)bh << 20) + (long)s0 * 1024;

    // q fragments: 2 row-tiles x 2 K-chunks
    short8 qa00 = *(const short8*)(qbase + (s0 + ln) * 64 + qd * 8);
    short8 qa01 = *(const short8*)(qbase + (s0 + ln) * 64 + 32 + qd * 8);
    short8 qa10 = *(const short8*)(qbase + (s0 + 16 + ln) * 64 + qd * 8);
    short8 qa11 = *(const short8*)(qbase + (s0 + 16 + ln) * 64 + 32 + qd * 8);

    // ---- Phase A1: content ----
    for (int tt = 0; tt < 16; tt++) {
        int t0 = c0 + tt * 16;
        const u16* kp = kbase + (t0 + ln) * 64 + qd * 8;
        short8 kb0 = *(const short8*)(kp);
        short8 kb1 = *(const short8*)(kp + 32);
        f32x4 a0 = {}, a1 = {};
        a0 = MFMA16(qa00, kb0, a0);
        a0 = MFMA16(qa01, kb1, a0);
        a1 = MFMA16(qa10, kb0, a1);
        a1 = MFMA16(qa11, kb1, a1);
        int t = t0 + ln;
#pragma unroll
        for (int r = 0; r < 4; r++) {
            int sl = qd * 4 + r;
            cont_base[sl * 1024 + t] = a0[r];
            cont_base[(sl + 16) * 1024 + t] = a1[r];
            sc[sl][SW(sl, t)] = f2bf(a0[r] * SCALE);
            sc[sl + 16][SW(sl + 16, t)] = f2bf(a1[r] * SCALE);
        }
    }

    // ---- Phase A2: pos band (wave-private, no barrier needed) ----
    int rbase = 1008 - s0;
    for (int rt = 16 * w - 1; rt <= 16 * w + 16; rt++) {
        int r0 = rbase + rt * 16; // min 0 (s0=992,w=0,rt=-1); max+ln = 2047
        const u16* rp = relws + (r0 + ln) * 64 + qd * 8;
        short8 rb0 = *(const short8*)(rp);
        short8 rb1 = *(const short8*)(rp + 32);
        f32x4 a0 = {}, a1 = {};
        a0 = MFMA16(qa00, rb0, a0);
        a0 = MFMA16(qa01, rb1, a0);
        a1 = MFMA16(qa10, rb0, a1);
        a1 = MFMA16(qa11, rb1, a1);
#pragma unroll
        for (int r = 0; r < 4; r++) {
            int sl = qd * 4 + r;
            int t = rt * 16 + ln + sl - 15; // row-tile 0
            if (t >= c0 && t < c0 + 256) {
                pos_base[sl * 1024 + t] = a0[r];
                u16 cur = sc[sl][SW(sl, t)];
                float fv = __uint_as_float((u32)cur << 16) + a0[r] * SCALE;
                sc[sl][SW(sl, t)] = f2bf(fv);
            }
            int t1 = t + 16;                // row-tile 1
            if (t1 >= c0 && t1 < c0 + 256) {
                pos_base[(sl + 16) * 1024 + t1] = a1[r];
                u16 cur = sc[sl + 16][SW(sl + 16, t1)];
                float fv = __uint_as_float((u32)cur << 16) + a1[r] * SCALE;
                sc[sl + 16][SW(sl + 16, t1)] = f2bf(fv);
            }
        }
    }
    __syncthreads();

    // ---- Phase B: softmax, 8 threads/row over 32 rows ----
    {
        int row = tid >> 3, gg = tid & 7;
        float sum = 0.f;
#pragma unroll
        for (int ii = 0; ii < 64; ii++) {
            int c = 2 * gg + 16 * ii;
            u32 pk = *(const u32*)&sc[row][SW(row, c)];
            float e0 = __expf(__uint_as_float(pk << 16));
            float e1 = __expf(__uint_as_float(pk & 0xffff0000u));
            sum += e0 + e1;
            u32 pe;
            asm("v_cvt_pk_bf16_f32 %0, %1, %2" : "=v"(pe) : "v"(e0), "v"(e1));
            *(u32*)&sc[row][SW(row, c)] = pe; // in place: this u32 is ours
        }
        sum += __shfl_xor(sum, 1, 8);
        sum += __shfl_xor(sum, 2, 8);
        sum += __shfl_xor(sum, 4, 8);
        float inv = 1.0f / sum;
        if (gg == 0) sinvws[((long)bh << 10) + s0 + row] = inv;
#pragma unroll
        for (int ii = 0; ii < 64; ii++) {
            int c = 2 * gg + 16 * ii;
            u32 pk = *(const u32*)&sc[row][SW(row, c)];
            f32x2 av = {__uint_as_float(pk << 16) * inv,
                        __uint_as_float(pk & 0xffff0000u) * inv};
            *(f32x2*)&attn_base[row * 1024 + c] = av;
        }
    }
    __syncthreads();

    // ---- Phase C: PV. Wave w -> d-subtile [w*16, w*16+16), both row-tiles.
    {
        float inv0[4], inv1[4]; // written pre-barrier by this block
#pragma unroll
        for (int r = 0; r < 4; r++) {
            inv0[r] = sinvws[((long)bh << 10) + s0 + qd * 4 + r];
            inv1[r] = sinvws[((long)bh << 10) + s0 + 16 + qd * 4 + r];
        }
        const u16* vrow = vtbase + (w * 16 + ln) * 1024 + qd * 8;
        f32x4 oa00 = {}, oa01 = {}, oa10 = {}, oa11 = {};
#pragma unroll
        for (int kt = 0; kt < 32; kt += 2) {
            int ca = kt * 32 + qd * 8;
            int cb = ca + 32;
            short8 a0  = *(const short8*)&sc[ln][SW(ln, ca)];
            short8 a1  = *(const short8*)&sc[ln + 16][SW(ln + 16, ca)];
            short8 b0  = *(const short8*)(vrow + kt * 32);
            short8 a0b = *(const short8*)&sc[ln][SW(ln, cb)];
            short8 a1b = *(const short8*)&sc[ln + 16][SW(ln + 16, cb)];
            short8 b1  = *(const short8*)(vrow + kt * 32 + 32);
            oa00 = MFMA16(a0, b0, oa00);
            oa10 = MFMA16(a1, b0, oa10);
            oa01 = MFMA16(a0b, b1, oa01);
            oa11 = MFMA16(a1b, b1, oa11);
        }
        int d = w * 16 + ln;
#pragma unroll
        for (int r = 0; r < 4; r++) {
            int sl = qd * 4 + r;
            ctx[((long)(b * 1024 + s0 + sl)) * 512 + h * 64 + d] =
                f2bf((oa00[r] + oa01[r]) * inv0[r]);
            ctx[((long)(b * 1024 + s0 + 16 + sl)) * 512 + h * 64 + d] =
                f2bf((oa10[r] + oa11[r]) * inv1[r]);
        }
    }
}

extern "C" void kernel_launch(void* const* d_in, const int* in_sizes, int n_in,
                              void* d_out, int out_size, void* d_ws, size_t ws_size,
                              hipStream_t stream) {
    (void)in_sizes; (void)n_in; (void)out_size; (void)ws_size;
    const float* query   = (const float*)d_in[0];
    const float* key     = (const float*)d_in[1];
    const float* value   = (const float*)d_in[2];
    const float* pos_emb = (const float*)d_in[3];
    const float* Wq = (const float*)d_in[4];
    const float* bq = (const float*)d_in[5];
    const float* Wk = (const float*)d_in[6];
    const float* bk = (const float*)d_in[7];
    const float* Wv = (const float*)d_in[8];
    const float* bv = (const float*)d_in[9];
    const float* Wo = (const float*)d_in[10];
    const float* bo = (const float*)d_in[11];
    const float* Wp = (const float*)d_in[12];
    const float* bp = (const float*)d_in[13];

    // workspace layout (bf16 u16 elements)
    u16* qin  = (u16*)d_ws;            // 4096*512
    u16* kin  = qin + 4096 * 512;
    u16* vin  = kin + 4096 * 512;
    u16* wqb  = vin + 4096 * 512;      // 512*512 each
    u16* wkb  = wqb + 512 * 512;
    u16* wvb  = wkb + 512 * 512;
    u16* wob  = wvb + 512 * 512;
    u16* relb = wob + 512 * 512;       // 2048*64 (row 2047 read-garbage, discarded)
    u16* qws  = relb + 2048 * 64;      // [B,H,S,64]
    u16* kws  = qws + 4 * 8 * 1024 * 64;
    u16* vtws = kws + 4 * 8 * 1024 * 64; // [B,H,64,S]
    u16* ctx  = qin;                   // alias: qin dead after q-projection
    float* sinvws = (float*)kin;       // alias: kin dead after k-projection

    float* out  = (float*)d_out;
    float* attn = out + 2097152;
    float* cont = attn + 33554432;
    float* pos  = cont + 33554432;

    cvt_kernel<<<2048, 256, 0, stream>>>(query, qin, 524288);
    cvt_kernel<<<2048, 256, 0, stream>>>(key, kin, 524288);
    cvt_kernel<<<2048, 256, 0, stream>>>(value, vin, 524288);
    cvt_kernel<<<256, 256, 0, stream>>>(Wq, wqb, 65536);
    cvt_kernel<<<256, 256, 0, stream>>>(Wk, wkb, 65536);
    cvt_kernel<<<256, 256, 0, stream>>>(Wv, wvb, 65536);
    cvt_kernel<<<256, 256, 0, stream>>>(Wo, wob, 65536);
    rel_kernel<<<512, 256, 0, stream>>>(pos_emb, Wp, bp, relb);

    gemm_kernel<0><<<dim3(64, 8), 256, 0, stream>>>(qin, wqb, bq, qws, 4096, 512, 512);
    gemm_kernel<0><<<dim3(64, 8), 256, 0, stream>>>(kin, wkb, bk, kws, 4096, 512, 512);
    gemm_v_kernel<<<512, 256, 0, stream>>>(wvb, vin, bv, vtws);

    score_kernel<<<1024, 256, 0, stream>>>(qws, kws, vtws, relb,
                                           attn, cont, pos, ctx, sinvws);

    gemm_kernel<2><<<dim3(64, 8), 256, 0, stream>>>(ctx, wob, bo, out, 4096, 512, 512);
}